// Round 3
// baseline (471.691 us; speedup 1.0000x reference)
//
#include <hip/hip_runtime.h>

// EEG preprocessor: x (B=256, C=128, T=2048) fp32
//   1) subtract channel-mean per (b,t)
//   2) z-score over time per (b,c), std==0 -> divide by 1
//
// R3: back to two streaming kernels, informed by R2's counters:
//  - R2 (fused, grid=256 = 1 block/CU) proved L3 retains all 256 MiB of x
//    across the re-read (FETCH_SIZE == 256 MiB for 512 MiB of reads), but
//    ran at 178us vs the ~84us traffic roofline: with no block queue, each
//    CU serializes phase1 -> barrier -> phase2 and HBM never overlaps
//    reads with writes. Occupancy 36%, VALUBusy 7.6% => structure-bound.
//  - R1 vs R2 showed the harness poison fills (~288us) are UNCONDITIONAL:
//    not using d_ws saves nothing. So d_ws is free — use it for mu.
//  - Two kernels give deep per-CU block queues (8 resident + queued) and
//    natural read/write overlap. x stays L3-resident across the kernel
//    boundary (input == 256 MiB == Infinity Cache), so kernel B's x reads
//    are L3 hits; its stores are nontemporal so they don't evict x.

#define B 256
#define C 128
#define T 2048
#define T4 (T / 4)  // 512 float4 per (b,c) row

typedef float f4 __attribute__((ext_vector_type(4)));

// ---- Kernel A: mu[b,t] = mean over channels (verified in R1) ----
__launch_bounds__(256)
__global__ void mu_kernel(const float* __restrict__ x, float* __restrict__ mu) {
    const int b = blockIdx.y;
    const int t0 = blockIdx.x * 256;       // 256 t's per block
    const int tid = threadIdx.x;
    const int wave = tid >> 6;
    const int lane = tid & 63;

    // wave w reduces channels [32w, 32w+32) for t in [t0, t0+256)
    const float4* __restrict__ xp =
        reinterpret_cast<const float4*>(x + ((size_t)b * C + wave * 32) * T + t0);

    float4 acc = make_float4(0.f, 0.f, 0.f, 0.f);
    #pragma unroll 8
    for (int k = 0; k < 32; ++k) {
        float4 v = xp[(size_t)k * T4 + lane];
        acc.x += v.x; acc.y += v.y; acc.z += v.z; acc.w += v.w;
    }

    __shared__ float4 part[4][64];
    part[wave][lane] = acc;
    __syncthreads();

    if (wave == 0) {
        float4 p0 = part[0][lane], p1 = part[1][lane];
        float4 p2 = part[2][lane], p3 = part[3][lane];
        const float invC = 1.0f / (float)C;
        float4 s;
        s.x = (p0.x + p1.x + p2.x + p3.x) * invC;
        s.y = (p0.y + p1.y + p2.y + p3.y) * invC;
        s.z = (p0.z + p1.z + p2.z + p3.z) * invC;
        s.w = (p0.w + p1.w + p2.w + p3.w) * invC;
        reinterpret_cast<float4*>(mu + (size_t)b * T + t0)[lane] = s;
    }
}

// ---- Kernel B: one WAVE per (b,c) row. No LDS, no barriers. ----
__launch_bounds__(256)
__global__ void zscore_wave(const float* __restrict__ x,
                            const float* __restrict__ mu,
                            float* __restrict__ out) {
    const int wave = threadIdx.x >> 6;
    const int lane = threadIdx.x & 63;
    const int bc = blockIdx.x * 4 + wave;  // b*C + c
    const int b = bc >> 7;

    const float4* __restrict__ xc = reinterpret_cast<const float4*>(x) + (size_t)bc * T4;
    const float4* __restrict__ mc = reinterpret_cast<const float4*>(mu) + (size_t)b * T4;

    float4 y[8];
    float sum = 0.f, sq = 0.f;
    #pragma unroll
    for (int j = 0; j < 8; ++j) {
        float4 v = xc[lane + j * 64];
        float4 m = mc[lane + j * 64];
        y[j].x = v.x - m.x; y[j].y = v.y - m.y;
        y[j].z = v.z - m.z; y[j].w = v.w - m.w;
        sum += (y[j].x + y[j].y) + (y[j].z + y[j].w);
        sq  += (y[j].x * y[j].x + y[j].y * y[j].y)
             + (y[j].z * y[j].z + y[j].w * y[j].w);
    }

    // wave64 butterfly: every lane ends with the row totals
    #pragma unroll
    for (int off = 32; off > 0; off >>= 1) {
        sum += __shfl_xor(sum, off, 64);
        sq  += __shfl_xor(sq,  off, 64);
    }

    const float invT = 1.0f / (float)T;
    float mean = sum * invT;
    float var  = fmaxf(sq * invT - mean * mean, 0.f);
    float sd   = sqrtf(var);
    float inv  = (sd == 0.f) ? 1.0f : 1.0f / sd;

    float4* __restrict__ oc = reinterpret_cast<float4*>(out) + (size_t)bc * T4;
    #pragma unroll
    for (int j = 0; j < 8; ++j) {
        f4 o = { (y[j].x - mean) * inv,
                 (y[j].y - mean) * inv,
                 (y[j].z - mean) * inv,
                 (y[j].w - mean) * inv };
        __builtin_nontemporal_store(o, reinterpret_cast<f4*>(oc + lane + j * 64));
    }
}

extern "C" void kernel_launch(void* const* d_in, const int* in_sizes, int n_in,
                              void* d_out, int out_size, void* d_ws, size_t ws_size,
                              hipStream_t stream) {
    const float* x = (const float*)d_in[0];
    float* out = (float*)d_out;
    float* mu = (float*)d_ws;  // B*T floats = 2 MiB

    dim3 gridA(T / 256, B);
    mu_kernel<<<gridA, 256, 0, stream>>>(x, mu);
    zscore_wave<<<(B * C) / 4, 256, 0, stream>>>(x, mu, out);
}

// Round 4
// 464.842 us; speedup vs baseline: 1.0147x; 1.0147x over previous
//
#include <hip/hip_runtime.h>

// EEG preprocessor: x (B=256, C=128, T=2048) fp32
//   1) subtract channel-mean per (b,t)
//   2) z-score over time per (b,c), std==0 -> divide by 1
//
// R4: fused (R2 base, best measured) + register/LDS stash to cut the L3
// re-read. Evidence trail:
//  - R1/R2/R3: three different structures all give ~180-190us kernel time
//    (fixed harness overhead ~288us). Occupancy/queue depth is NOT the
//    limiter (R3 falsified that).
//  - R2 counters: FETCH==256 MiB proves phase-2 x reads are L3-served,
//    yet only 3 TB/s HBM => the L3 re-read at ~2 TB/s effective is the
//    binding constraint.
//  - x (256 MiB) can't fit on-chip; but per-block (batch=1 MiB) we can
//    stash 48/128 rows during phase 1: 16 rows/group in VGPRs (v[16]) +
//    16 rows in LDS (128 KiB). L3 re-read: 256 -> 160 MiB.
//  - Stashed rows are the EARLIEST-read (coldest by phase 2); re-read
//    rows processed hottest-first.

#define B 256
#define C 128
#define T 2048
#define T4 (T / 4)  // 512 float4 per (b,c) row

typedef float f4 __attribute__((ext_vector_type(4)));

__launch_bounds__(1024, 4)
__global__ void eeg_fused3(const float* __restrict__ x, float* __restrict__ out) {
    const int b = blockIdx.x;
    const int tid = threadIdx.x;
    const int t4 = tid & (T4 - 1);   // float4 column
    const int g  = tid >> 9;         // channel group: 0 -> c[0,64), 1 -> c[64,128)
    const int wave = tid >> 6;       // 0..15
    const int lane = tid & 63;

    __shared__ float4 mu4[T4];        // 8 KiB
    __shared__ float4 part[T4];       // 8 KiB (phase-1 partial; reused as stat-combine)
    __shared__ float4 stash[16][T4];  // 128 KiB: rows {16..23, 80..87}
    __shared__ float2 finals[32];     // mean, 1/sd for the 32 register rows

    const float4* __restrict__ xb =
        reinterpret_cast<const float4*>(x) + (size_t)b * C * T4;
    float4* __restrict__ ob =
        reinterpret_cast<float4*>(out) + (size_t)b * C * T4;

    // ---- Phase 1: mu over channels; stash rows on the way through ----
    const float4* __restrict__ xp = xb + (size_t)(g * 64) * T4 + t4;
    float4 acc = make_float4(0.f, 0.f, 0.f, 0.f);
    float4 v[16];                     // register stash: channels g*64 + [0,16)
    #pragma unroll
    for (int k = 0; k < 16; ++k) {
        v[k] = xp[(size_t)k * T4];
        acc.x += v[k].x; acc.y += v[k].y; acc.z += v[k].z; acc.w += v[k].w;
    }
    #pragma unroll
    for (int k = 16; k < 24; ++k) {   // LDS stash: channels g*64 + [16,24)
        float4 w = xp[(size_t)k * T4];
        stash[(g << 3) + (k - 16)][t4] = w;
        acc.x += w.x; acc.y += w.y; acc.z += w.z; acc.w += w.w;
    }
    #pragma unroll 8
    for (int k = 24; k < 64; ++k) {   // stream-only
        float4 w = xp[(size_t)k * T4];
        acc.x += w.x; acc.y += w.y; acc.z += w.z; acc.w += w.w;
    }
    if (g) part[t4] = acc;
    else   mu4[t4]  = acc;
    __syncthreads();
    if (!g) {
        const float invC = 1.0f / (float)C;
        float4 p = part[t4], m0 = mu4[t4];
        m0.x = (m0.x + p.x) * invC; m0.y = (m0.y + p.y) * invC;
        m0.z = (m0.z + p.z) * invC; m0.w = (m0.w + p.w) * invC;
        mu4[t4] = m0;
    }
    __syncthreads();

    // ---- Phase 2a: the 32 register rows (never re-read) ----
    const float4 m = mu4[t4];
    float2* comb = reinterpret_cast<float2*>(part);  // [16 waves][16 k]
    #pragma unroll
    for (int k = 0; k < 16; ++k) {
        float yx = v[k].x - m.x, yy = v[k].y - m.y;
        float yz = v[k].z - m.z, yw = v[k].w - m.w;
        float s = (yx + yy) + (yz + yw);
        float q = (yx * yx + yy * yy) + (yz * yz + yw * yw);
        #pragma unroll
        for (int off = 32; off > 0; off >>= 1) {
            s += __shfl_xor(s, off, 64);
            q += __shfl_xor(q, off, 64);
        }
        if (lane == 0) comb[wave * 16 + k] = make_float2(s, q);
    }
    __syncthreads();
    if (tid < 32) {                   // one thread per register row
        const int gg = tid >> 4, kk = tid & 15;
        float s = 0.f, q = 0.f;
        #pragma unroll
        for (int w = 0; w < 8; ++w) { // combine the 8 waves of group gg
            float2 c2 = comb[(gg * 8 + w) * 16 + kk];
            s += c2.x; q += c2.y;
        }
        const float invT = 1.0f / (float)T;
        float mean = s * invT;
        float var  = fmaxf(q * invT - mean * mean, 0.f);
        float sd   = sqrtf(var);
        finals[tid] = make_float2(mean, (sd == 0.f) ? 1.0f : 1.0f / sd);
    }
    __syncthreads();
    #pragma unroll
    for (int k = 0; k < 16; ++k) {
        float2 f = finals[g * 16 + k];
        f4 o = { (v[k].x - m.x - f.x) * f.y,
                 (v[k].y - m.y - f.x) * f.y,
                 (v[k].z - m.z - f.x) * f.y,
                 (v[k].w - m.w - f.x) * f.y };
        __builtin_nontemporal_store(
            o, reinterpret_cast<f4*>(ob + (size_t)(g * 64 + k) * T4 + t4));
    }

    // ---- Phase 2a': the 16 LDS-stashed rows, one per wave ----
    {
        const int si = wave;
        const int ch = (si < 8) ? (16 + si) : (72 + si);  // 16..23, 80..87
        float4 yv[8];
        float s = 0.f, q = 0.f;
        #pragma unroll
        for (int j = 0; j < 8; ++j) {
            float4 vv = stash[si][lane + j * 64];
            float4 mm = mu4[lane + j * 64];
            yv[j].x = vv.x - mm.x; yv[j].y = vv.y - mm.y;
            yv[j].z = vv.z - mm.z; yv[j].w = vv.w - mm.w;
            s += (yv[j].x + yv[j].y) + (yv[j].z + yv[j].w);
            q += (yv[j].x * yv[j].x + yv[j].y * yv[j].y)
               + (yv[j].z * yv[j].z + yv[j].w * yv[j].w);
        }
        #pragma unroll
        for (int off = 32; off > 0; off >>= 1) {
            s += __shfl_xor(s, off, 64);
            q += __shfl_xor(q, off, 64);
        }
        const float invT = 1.0f / (float)T;
        float mean = s * invT;
        float var  = fmaxf(q * invT - mean * mean, 0.f);
        float sd   = sqrtf(var);
        float inv  = (sd == 0.f) ? 1.0f : 1.0f / sd;
        float4* __restrict__ oc = ob + (size_t)ch * T4;
        #pragma unroll
        for (int j = 0; j < 8; ++j) {
            f4 o = { (yv[j].x - mean) * inv, (yv[j].y - mean) * inv,
                     (yv[j].z - mean) * inv, (yv[j].w - mean) * inv };
            __builtin_nontemporal_store(o, reinterpret_cast<f4*>(oc + lane + j * 64));
        }
    }

    // ---- Phase 2b: 80 re-read rows (L3), hottest-first, 5 per wave ----
    const float invT = 1.0f / (float)T;
    for (int i = 0; i < 5; ++i) {
        const int idx = i * 16 + wave;              // 0..79
        const int c = (idx < 40) ? (127 - idx) : (103 - idx);  // 127..88, 63..24
        const float4* __restrict__ xc = xb + (size_t)c * T4;

        float4 y[8];
        float s = 0.f, q = 0.f;
        #pragma unroll
        for (int j = 0; j < 8; ++j) {
            float4 vv = xc[lane + j * 64];
            float4 mm = mu4[lane + j * 64];
            y[j].x = vv.x - mm.x; y[j].y = vv.y - mm.y;
            y[j].z = vv.z - mm.z; y[j].w = vv.w - mm.w;
            s += (y[j].x + y[j].y) + (y[j].z + y[j].w);
            q += (y[j].x * y[j].x + y[j].y * y[j].y)
               + (y[j].z * y[j].z + y[j].w * y[j].w);
        }
        #pragma unroll
        for (int off = 32; off > 0; off >>= 1) {
            s += __shfl_xor(s, off, 64);
            q += __shfl_xor(q, off, 64);
        }
        float mean = s * invT;
        float var  = fmaxf(q * invT - mean * mean, 0.f);
        float sd   = sqrtf(var);
        float inv  = (sd == 0.f) ? 1.0f : 1.0f / sd;

        float4* __restrict__ oc = ob + (size_t)c * T4;
        #pragma unroll
        for (int j = 0; j < 8; ++j) {
            f4 o = { (y[j].x - mean) * inv, (y[j].y - mean) * inv,
                     (y[j].z - mean) * inv, (y[j].w - mean) * inv };
            __builtin_nontemporal_store(o, reinterpret_cast<f4*>(oc + lane + j * 64));
        }
    }
}

extern "C" void kernel_launch(void* const* d_in, const int* in_sizes, int n_in,
                              void* d_out, int out_size, void* d_ws, size_t ws_size,
                              hipStream_t stream) {
    const float* x = (const float*)d_in[0];
    float* out = (float*)d_out;
    (void)d_ws; (void)ws_size;

    eeg_fused3<<<B, 1024, 0, stream>>>(x, out);
}